// Round 3
// baseline (257.149 us; speedup 1.0000x reference)
//
#include <hip/hip_runtime.h>

// Shapes (fixed by the problem)
#define B_N    8
#define S_LEN  16384
#define C_CH   256
#define CV     64            // float4 groups per s-row (C_CH/4)
#define L1_LEN 8195          // (16384+7)/2
#define L2_LEN 4101          // (8195+7)/2
#define T2S    8             // level-2 outputs per wave (sub-tile)
#define TILE   32            // level-2 outputs per block (4 waves)
#define NTILES 129           // ceil(4101/32)

typedef float v4 __attribute__((ext_vector_type(4)));

// Symmetric (edge-inclusive) reflection, single bounce (halo << L)
__device__ __forceinline__ int refl(int n, int L) {
  n = (n < 0) ? (-n - 1) : n;
  n = (n >= L) ? (2 * L - 1 - n) : n;
  return n;
}

__device__ __forceinline__ v4 vfma(float s, v4 a, v4 c) {
  c.x = fmaf(s, a.x, c.x);
  c.y = fmaf(s, a.y, c.y);
  c.z = fmaf(s, a.z, c.z);
  c.w = fmaf(s, a.w, c.w);
  return c;
}

// Reversed db4 filters: R*[k] = DEC_*[7-k]; out[i] = sum_k R[k] * x_sym[2i-6+k]
__device__ constexpr float RLO[8] = {
   0.23037781330885523f,  0.7148465705525415f,   0.6308807679295904f,
  -0.02798376941698385f, -0.18703481171888114f,  0.030841381835986965f,
   0.032883011666982945f, -0.010597401784997278f };
__device__ constexpr float RHI[8] = {
  -0.010597401784997278f, -0.032883011666982945f, 0.030841381835986965f,
   0.18703481171888114f,  -0.02798376941698385f,  -0.6308807679295904f,
   0.7148465705525415f,   -0.23037781330885523f };

__global__ __launch_bounds__(256, 2)
void dwt2_fused(const float* __restrict__ xg,
                float* __restrict__ d1g,
                float* __restrict__ d2g,
                float* __restrict__ a2g) {
  const int lane = threadIdx.x & 63;   // channels 4*lane .. 4*lane+3
  const int wv   = threadIdx.x >> 6;   // sub-tile within block
  const int b    = blockIdx.y;
  const int a2w  = blockIdx.x * TILE + wv * T2S;  // first level-2 output of this wave
  if (a2w > 4096) return;              // tile 128, waves 1-3: no outputs

  const v4* __restrict__ xr  = (const v4*)xg + (size_t)b * S_LEN  * CV + lane;
  v4*       __restrict__ d1r = (v4*)d1g      + (size_t)b * L1_LEN * CV + lane;
  v4*       __restrict__ d2r = (v4*)d2g      + (size_t)b * L2_LEN * CV + lane;
  v4*       __restrict__ a2r = (v4*)a2g      + (size_t)b * L2_LEN * CV + lane;

  // Interior waves: x indices [4*a2w-18, 4*a2w+31] all within [0, S_LEN),
  // level-2 cA1 indices [2*a2w-6, 2*a2w+15] all within [0, L1_LEN).
  if (a2w >= 8 && a2w <= 4088) {
    // ---- fast streaming path (4126 of 4128 waves) ----
    v4 xw[8], aw[8];
    const int s0 = 4 * a2w - 18;
    #pragma unroll
    for (int k = 0; k < 8; ++k) xw[k] = xr[(s0 + k) * CV];

    // 6 halo cA1 values: aw[p] = cA1[2*a2w-6+p]   (no stores)
    #pragma unroll
    for (int p = 0; p < 6; ++p) {
      v4 a = {0.f, 0.f, 0.f, 0.f};
      #pragma unroll
      for (int k = 0; k < 8; ++k) a = vfma(RLO[k], xw[k], a);
      aw[p] = a;
      #pragma unroll
      for (int k = 0; k < 6; ++k) xw[k] = xw[k + 2];
      xw[6] = xr[(s0 + 8 + 2 * p) * CV];
      xw[7] = xr[(s0 + 9 + 2 * p) * CV];
    }
    // window now = x[4*a2w-6 .. 4*a2w+1]  → ready for i1 = 2*a2w

    int i1 = 2 * a2w;
    #pragma unroll
    for (int t = 0; t < T2S; ++t) {
      v4 a0 = {0.f,0.f,0.f,0.f}, d0 = {0.f,0.f,0.f,0.f};
      #pragma unroll
      for (int k = 0; k < 8; ++k) {
        a0 = vfma(RLO[k], xw[k], a0);
        d0 = vfma(RHI[k], xw[k], d0);
      }
      __builtin_nontemporal_store(d0, &d1r[i1 * CV]);

      #pragma unroll
      for (int k = 0; k < 6; ++k) xw[k] = xw[k + 2];
      xw[6] = xr[(2 * i1 + 2) * CV];
      xw[7] = xr[(2 * i1 + 3) * CV];

      v4 a1 = {0.f,0.f,0.f,0.f}, dv = {0.f,0.f,0.f,0.f};
      #pragma unroll
      for (int k = 0; k < 8; ++k) {
        a1 = vfma(RLO[k], xw[k], a1);
        dv = vfma(RHI[k], xw[k], dv);
      }
      __builtin_nontemporal_store(dv, &d1r[(i1 + 1) * CV]);

      if (t + 1 < T2S) {     // uniform, compile-time after unroll; skips 2 OOB prefetches
        #pragma unroll
        for (int k = 0; k < 6; ++k) xw[k] = xw[k + 2];
        xw[6] = xr[(2 * i1 + 4) * CV];
        xw[7] = xr[(2 * i1 + 5) * CV];
      }

      aw[6] = a0; aw[7] = a1;           // aw[k] = cA1[2*i2-6+k]
      v4 ca = {0.f,0.f,0.f,0.f}, cd = {0.f,0.f,0.f,0.f};
      #pragma unroll
      for (int k = 0; k < 8; ++k) {
        ca = vfma(RLO[k], aw[k], ca);
        cd = vfma(RHI[k], aw[k], cd);
      }
      const int i2 = a2w + t;
      __builtin_nontemporal_store(ca, &a2r[i2 * CV]);
      __builtin_nontemporal_store(cd, &d2r[i2 * CV]);
      #pragma unroll
      for (int k = 0; k < 6; ++k) aw[k] = aw[k + 2];

      i1 += 2;
    }
    return;
  }

  // ---- generic reflected path (2 waves: a2w==0 and a2w==4096) ----
  const int i1_0 = 2 * a2w;
  const int i1_e = min(2 * a2w + 2 * T2S, L1_LEN);
  for (int i1 = i1_0; i1 < i1_e; ++i1) {
    v4 d = {0.f,0.f,0.f,0.f};
    #pragma unroll
    for (int k = 0; k < 8; ++k)
      d = vfma(RHI[k], xr[refl(2 * i1 - 6 + k, S_LEN) * CV], d);
    __builtin_nontemporal_store(d, &d1r[i1 * CV]);
  }
  const int i2_e = min(a2w + T2S, L2_LEN);
  for (int i2 = a2w; i2 < i2_e; ++i2) {
    v4 ca = {0.f,0.f,0.f,0.f}, cd = {0.f,0.f,0.f,0.f};
    #pragma unroll
    for (int k = 0; k < 8; ++k) {
      const int m = refl(2 * i2 - 6 + k, L1_LEN);
      v4 a = {0.f,0.f,0.f,0.f};
      #pragma unroll
      for (int j = 0; j < 8; ++j)
        a = vfma(RLO[j], xr[refl(2 * m - 6 + j, S_LEN) * CV], a);
      ca = vfma(RLO[k], a, ca);
      cd = vfma(RHI[k], a, cd);
    }
    __builtin_nontemporal_store(ca, &a2r[i2 * CV]);
    __builtin_nontemporal_store(cd, &d2r[i2 * CV]);
  }
}

extern "C" void kernel_launch(void* const* d_in, const int* in_sizes, int n_in,
                              void* d_out, int out_size, void* d_ws, size_t ws_size,
                              hipStream_t stream) {
  const float* x = (const float*)d_in[0];
  float* out = (float*)d_out;
  float* d1 = out;                                   // cD1: 8*8195*256
  float* d2 = d1 + (size_t)B_N * L1_LEN * C_CH;      // cD2: 8*4101*256
  float* a2 = d2 + (size_t)B_N * L2_LEN * C_CH;      // cA2: 8*4101*256
  dim3 grid(NTILES, B_N);
  dwt2_fused<<<grid, dim3(256), 0, stream>>>(x, d1, d2, a2);
}

// Round 6
// 250.628 us; speedup vs baseline: 1.0260x; 1.0260x over previous
//
#include <hip/hip_runtime.h>

// Shapes (fixed by the problem)
#define B_N    8
#define S_LEN  16384
#define C_CH   256
#define CV     64            // float4 groups per s-row (C_CH/4)
#define L1_LEN 8195          // (16384+7)/2
#define L2_LEN 4101          // (8195+7)/2
#define T2     16            // level-2 outputs per block
#define ROWS   (2*T2 + 8)    // 40 cA1 rows staged in LDS (halo 6 left + 2 right)
#define NT2    257           // ceil(4101/16)

typedef float v4 __attribute__((ext_vector_type(4)));

// Symmetric (edge-inclusive) reflection, single bounce (halo << L)
__device__ __forceinline__ int refl(int n, int L) {
  n = (n < 0) ? (-n - 1) : n;
  n = (n >= L) ? (2 * L - 1 - n) : n;
  return n;
}

__device__ __forceinline__ v4 vfma(float s, v4 a, v4 c) {
  c.x = fmaf(s, a.x, c.x);
  c.y = fmaf(s, a.y, c.y);
  c.z = fmaf(s, a.z, c.z);
  c.w = fmaf(s, a.w, c.w);
  return c;
}

// Reversed db4 filters: R*[k] = DEC_*[7-k]; out[i] = sum_k R[k] * x_sym[2i-6+k]
__device__ constexpr float RLO[8] = {
   0.23037781330885523f,  0.7148465705525415f,   0.6308807679295904f,
  -0.02798376941698385f, -0.18703481171888114f,  0.030841381835986965f,
   0.032883011666982945f, -0.010597401784997278f };
__device__ constexpr float RHI[8] = {
  -0.010597401784997278f, -0.032883011666982945f, 0.030841381835986965f,
   0.18703481171888114f,  -0.02798376941698385f,  -0.6308807679295904f,
   0.7148465705525415f,   -0.23037781330885523f };

__global__ __launch_bounds__(256, 4)
void dwt2_fused(const float* __restrict__ xg,
                float* __restrict__ d1g,
                float* __restrict__ d2g,
                float* __restrict__ a2g) {
  const int lane = threadIdx.x & 63;   // channel v4-group
  const int w    = threadIdx.x >> 6;   // wave 0..3
  const int b    = blockIdx.y;
  const int a    = blockIdx.x * T2;    // first level-2 output index of block

  __shared__ v4 s_a1[ROWS][64];        // 40 KiB -> 4 blocks/CU

  const v4* __restrict__ xr  = (const v4*)xg + (size_t)b * S_LEN  * CV + lane;
  v4*       __restrict__ d1r = (v4*)d1g      + (size_t)b * L1_LEN * CV + lane;
  v4*       __restrict__ d2r = (v4*)d2g      + (size_t)b * L2_LEN * CV + lane;
  v4*       __restrict__ a2r = (v4*)a2g      + (size_t)b * L2_LEN * CV + lane;

  // ---- phase 1: level-1. Row m of LDS holds cA1_sym[(2a-6)+m], m=0..39.
  // Wave w handles m = 4j+w (adjacent waves -> adjacent x windows, L1-friendly).
  // All indices go through refl(): uniform SALU work, no edge/interior split.
  #pragma unroll 2
  for (int j = 0; j < ROWS / 4; ++j) {
    const int m   = 4 * j + w;
    const int i1n = 2 * a - 6 + m;              // nominal (may be OOB)
    const int i1  = refl(i1n, L1_LEN);          // cA1_sym[i1n] = cA1[i1]
    v4 xv[8];
    #pragma unroll
    for (int k = 0; k < 8; ++k)                 // 8 independent loads, burst
      xv[k] = xr[(size_t)refl(2 * i1 - 6 + k, S_LEN) * CV];
    v4 ca = {0.f,0.f,0.f,0.f}, cd = {0.f,0.f,0.f,0.f};
    #pragma unroll
    for (int k = 0; k < 8; ++k) {
      ca = vfma(RLO[k], xv[k], ca);
      cd = vfma(RHI[k], xv[k], cd);
    }
    s_a1[m][lane] = ca;
    // store cD1 exactly for i1n in [2a, 2a+2*T2) clipped to [0, L1_LEN)
    if (m >= 6 && m < 6 + 2 * T2 && i1n < L1_LEN)
      __builtin_nontemporal_store(cd, &d1r[(size_t)i1n * CV]);
  }
  __syncthreads();

  // ---- phase 2: level-2 from LDS. Wave w handles i2 = a + 4w + j2.
  #pragma unroll
  for (int j2 = 0; j2 < 4; ++j2) {
    const int io = 4 * w + j2;                  // i2 - a, 0..15
    const int i2 = a + io;
    v4 ca = {0.f,0.f,0.f,0.f}, cd = {0.f,0.f,0.f,0.f};
    #pragma unroll
    for (int k = 0; k < 8; ++k) {               // row 2*io+k in [0, 37]
      const v4 av = s_a1[2 * io + k][lane];
      ca = vfma(RLO[k], av, ca);
      cd = vfma(RHI[k], av, cd);
    }
    if (i2 < L2_LEN) {
      __builtin_nontemporal_store(ca, &a2r[(size_t)i2 * CV]);
      __builtin_nontemporal_store(cd, &d2r[(size_t)i2 * CV]);
    }
  }
}

extern "C" void kernel_launch(void* const* d_in, const int* in_sizes, int n_in,
                              void* d_out, int out_size, void* d_ws, size_t ws_size,
                              hipStream_t stream) {
  const float* x = (const float*)d_in[0];
  float* out = (float*)d_out;
  float* d1 = out;                                   // cD1: 8*8195*256
  float* d2 = d1 + (size_t)B_N * L1_LEN * C_CH;      // cD2: 8*4101*256
  float* a2 = d2 + (size_t)B_N * L2_LEN * C_CH;      // cA2: 8*4101*256
  dim3 grid(NT2, B_N);
  dwt2_fused<<<grid, dim3(256), 0, stream>>>(x, d1, d2, a2);
}

// Round 9
// 239.439 us; speedup vs baseline: 1.0740x; 1.0467x over previous
//
#include <hip/hip_runtime.h>

// Shapes (fixed by the problem)
#define B_N    8
#define S_LEN  16384
#define C_CH   256
#define CV     64            // float4 groups per s-row (C_CH/4)
#define L1_LEN 8195          // (16384+7)/2
#define L2_LEN 4101          // (8195+7)/2
#define T2     8             // level-2 outputs per block
#define ROWS   (2*T2 + 8)    // 24 cA1 rows in LDS -> 24 KiB -> 5 blocks/CU
#define NJ     (ROWS/4)      // 6 phase-1 iterations per wave
#define NT2    513           // ceil(4101/8)

typedef float v4 __attribute__((ext_vector_type(4)));

// Symmetric (edge-inclusive) reflection, single bounce (halo << L)
__device__ __forceinline__ int refl(int n, int L) {
  n = (n < 0) ? (-n - 1) : n;
  n = (n >= L) ? (2 * L - 1 - n) : n;
  return n;
}

__device__ __forceinline__ v4 vfma(float s, v4 a, v4 c) {
  c.x = fmaf(s, a.x, c.x);
  c.y = fmaf(s, a.y, c.y);
  c.z = fmaf(s, a.z, c.z);
  c.w = fmaf(s, a.w, c.w);
  return c;
}

// Reversed db4 filters: R*[k] = DEC_*[7-k]; out[i] = sum_k R[k] * x_sym[2i-6+k]
__device__ constexpr float RLO[8] = {
   0.23037781330885523f,  0.7148465705525415f,   0.6308807679295904f,
  -0.02798376941698385f, -0.18703481171888114f,  0.030841381835986965f,
   0.032883011666982945f, -0.010597401784997278f };
__device__ constexpr float RHI[8] = {
  -0.010597401784997278f, -0.032883011666982945f, 0.030841381835986965f,
   0.18703481171888114f,  -0.02798376941698385f,  -0.6308807679295904f,
   0.7148465705525415f,   -0.23037781330885523f };

__global__ __launch_bounds__(256, 5)
void dwt2_fused(const float* __restrict__ xg,
                float* __restrict__ d1g,
                float* __restrict__ d2g,
                float* __restrict__ a2g) {
  const int lane = threadIdx.x & 63;   // channel v4-group
  const int w    = threadIdx.x >> 6;   // wave 0..3
  const int b    = blockIdx.y;
  const int a    = blockIdx.x * T2;    // first level-2 output index of block

  __shared__ v4 s_a1[ROWS][64];        // 24 KiB -> 5 blocks/CU (20 waves)

  const v4* __restrict__ xr  = (const v4*)xg + (size_t)b * S_LEN  * CV + lane;
  v4*       __restrict__ d1r = (v4*)d1g      + (size_t)b * L1_LEN * CV + lane;
  v4*       __restrict__ d2r = (v4*)d2g      + (size_t)b * L2_LEN * CV + lane;
  v4*       __restrict__ a2r = (v4*)a2g      + (size_t)b * L2_LEN * CV + lane;

  // ---- phase 1: level-1. LDS row m holds cA1_sym[(2a-6)+m]; wave w: m = 4j+w.
  // 2-row software pipeline: row j+1's 8 loads are issued before row j's FMAs.
  v4 xv[2][8];                         // (j&1) is compile-time after full unroll
  {
    const int i1 = refl(2 * a - 6 + w, L1_LEN);
    #pragma unroll
    for (int k = 0; k < 8; ++k)
      xv[0][k] = xr[(size_t)refl(2 * i1 - 6 + k, S_LEN) * CV];
  }
  #pragma unroll
  for (int j = 0; j < NJ; ++j) {
    if (j + 1 < NJ) {                  // prefetch next row
      const int i1 = refl(2 * a - 6 + 4 * (j + 1) + w, L1_LEN);
      #pragma unroll
      for (int k = 0; k < 8; ++k)
        xv[(j + 1) & 1][k] = xr[(size_t)refl(2 * i1 - 6 + k, S_LEN) * CV];
    }
    v4 ca = {0.f,0.f,0.f,0.f}, cd = {0.f,0.f,0.f,0.f};
    #pragma unroll
    for (int k = 0; k < 8; ++k) {
      ca = vfma(RLO[k], xv[j & 1][k], ca);
      cd = vfma(RHI[k], xv[j & 1][k], cd);
    }
    const int m   = 4 * j + w;
    const int i1n = 2 * a - 6 + m;     // nominal index (may be OOB at edges)
    s_a1[m][lane] = ca;
    // store cD1 exactly for i1n in [2a, 2a+2*T2) clipped to [0, L1_LEN)
    if (m >= 6 && m < 6 + 2 * T2 && i1n < L1_LEN)
      d1r[(size_t)i1n * CV] = cd;      // plain cached store
  }
  __syncthreads();

  // ---- phase 2: level-2 from LDS. Wave w handles io = 2w + j2, j2=0..1.
  #pragma unroll
  for (int j2 = 0; j2 < 2; ++j2) {
    const int io = 2 * w + j2;         // i2 - a, 0..7
    const int i2 = a + io;
    v4 ca = {0.f,0.f,0.f,0.f}, cd = {0.f,0.f,0.f,0.f};
    #pragma unroll
    for (int k = 0; k < 8; ++k) {      // row 2*io+k in [0, 21]
      const v4 av = s_a1[2 * io + k][lane];
      ca = vfma(RLO[k], av, ca);
      cd = vfma(RHI[k], av, cd);
    }
    if (i2 < L2_LEN) {
      a2r[(size_t)i2 * CV] = ca;       // plain cached stores
      d2r[(size_t)i2 * CV] = cd;
    }
  }
}

extern "C" void kernel_launch(void* const* d_in, const int* in_sizes, int n_in,
                              void* d_out, int out_size, void* d_ws, size_t ws_size,
                              hipStream_t stream) {
  const float* x = (const float*)d_in[0];
  float* out = (float*)d_out;
  float* d1 = out;                                   // cD1: 8*8195*256
  float* d2 = d1 + (size_t)B_N * L1_LEN * C_CH;      // cD2: 8*4101*256
  float* a2 = d2 + (size_t)B_N * L2_LEN * C_CH;      // cA2: 8*4101*256
  dim3 grid(NT2, B_N);
  dwt2_fused<<<grid, dim3(256), 0, stream>>>(x, d1, d2, a2);
}